// Round 13
// baseline (76.761 us; speedup 1.0000x reference)
//
#include <hip/hip_runtime.h>
#include <math.h>

#define MLEN 4096
#define RANK 8
#define NSAMP 2048
#define VEC 8      // consecutive m-points per thread
#define NS  4      // samples (n) per thread, reusing Hft loads

// ---------------------------------------------------------------------------
// MEASUREMENT ROUND 2: byte-identical to round 12 except mix_kernel launches
// 3x (idempotent). dur = fft4 + 3*mix; R12 gave fft4 + mix = 33.5
//   -> mix = (dur - 33.5)/2 ; fft4 = 33.5 - mix
// ---------------------------------------------------------------------------

__device__ __forceinline__ float softplus_f(float x) {
    return (x > 20.0f) ? x : log1pf(expf(x));
}

__device__ __forceinline__ float2 cmulf(float2 a, float2 b) {
    return make_float2(a.x * b.x - a.y * b.y, a.x * b.y + a.y * b.x);
}

__device__ __forceinline__ float2 wave_fft64(float2 v, int l) {
#pragma unroll
    for (int h = 32; h >= 1; h >>= 1) {
        const float tx = __shfl_xor(v.x, h);
        const float ty = __shfl_xor(v.y, h);
        const bool hi = (l & h) != 0;
        const float s = hi ? -1.0f : 1.0f;
        float2 u = make_float2(fmaf(s, v.x, tx), fmaf(s, v.y, ty));
        const int idx = hi ? (l & (h - 1)) : 0;
        const float ang = -3.14159265358979323846f * (float)idx / (float)h;
        const float cw = __cosf(ang), sw = __sinf(ang);
        v = make_float2(u.x * cw - u.y * sw, u.x * sw + u.y * cw);
    }
    return v;
}

__global__ __launch_bounds__(256) void fftA_kernel(const float* __restrict__ H,
                                                   float2* __restrict__ Z) {
    const int wid = (blockIdx.x << 2) + (threadIdx.x >> 6);  // 0..511
    const int l   = threadIdx.x & 63;                        // = n1
    const int d   = wid >> 6;
    const int n2  = wid & 63;

    const float x = softplus_f(H[d * MLEN + (l << 6) + n2]);
    float2 v = wave_fft64(make_float2(x, 0.0f), l);
    const int k1 = (int)(__brev((unsigned)l) >> 26);
    const float ang = -3.14159265358979323846f / 2048.0f * (float)(n2 * k1);
    v = cmulf(v, make_float2(__cosf(ang), __sinf(ang)));
    Z[d * MLEN + (k1 << 6) + n2] = v;
}

__global__ __launch_bounds__(256) void fftB_kernel(const float2* __restrict__ Z,
                                                   float2* __restrict__ Hft) {
    const int wid = (blockIdx.x << 2) + (threadIdx.x >> 6);  // 0..511
    const int l   = threadIdx.x & 63;                        // = n2
    const int d   = wid >> 6;
    const int k1  = wid & 63;

    float2 v = Z[d * MLEN + (k1 << 6) + l];
    v = wave_fft64(v, l);
    const int k2 = (int)(__brev((unsigned)l) >> 26);
    Hft[d * MLEN + (k2 << 6) + k1] = v;
}

template <int REAL_ONLY>
__device__ __forceinline__ void accum_rank(int d,
    const float4& h0, const float4& h1, const float4& h2, const float4& h3,
    const float* s_spw, const float* s_tau, const float2* s_step,
    float thm, float (&ar)[NS][VEC], float (&ai)[NS][VEC]) {
    float cs[NS], sn[NS], dc[NS], ds[NS];
#pragma unroll
    for (int j = 0; j < NS; ++j) {
        const float t   = s_tau[j * RANK + d];
        const float spw = s_spw[j * RANK + d];
        const float a0  = thm * t;
        cs[j] = spw * __cosf(a0);
        sn[j] = spw * __sinf(a0);
        const float2 st = s_step[j * RANK + d];
        dc[j] = st.x; ds[j] = st.y;
    }
#pragma unroll
    for (int k = 0; k < VEC; ++k) {
        const float4& hq = (k < 2) ? h0 : (k < 4) ? h1 : (k < 6) ? h2 : h3;
        const float hx = (k & 1) ? hq.z : hq.x;
        const float hy = (k & 1) ? hq.w : hq.y;
#pragma unroll
        for (int j = 0; j < NS; ++j) {
            ar[j][k] += cs[j] * hx - sn[j] * hy;
            if (!REAL_ONLY) ai[j][k] += cs[j] * hy + sn[j] * hx;
            if (k < VEC - 1) {
                const float ncs = cs[j] * dc[j] - sn[j] * ds[j];
                sn[j] = cs[j] * ds[j] + sn[j] * dc[j];
                cs[j] = ncs;
            }
        }
    }
}

template <int REAL_ONLY>
__global__ __launch_bounds__(256) void mix_kernel(const float* __restrict__ W,
                                                  const float* __restrict__ tau,
                                                  const float2* __restrict__ Hft,
                                                  float* __restrict__ out) {
    const int tid = threadIdx.x;
    const int m0  = (blockIdx.x * 256 + tid) * VEC;
    const int n0  = blockIdx.y * NS;

    __shared__ float  s_spw[NS * RANK];
    __shared__ float  s_tau[NS * RANK];
    __shared__ float2 s_step[NS * RANK];
    if (tid < NS * RANK) {
        const float t = tau[n0 * RANK + tid];
        s_spw[tid] = softplus_f(W[n0 * RANK + tid]);
        s_tau[tid] = t;
        const float a1 = -1.53398078788564122971e-3f * t;   // -2*pi/4096 * t
        s_step[tid] = make_float2(__cosf(a1), __sinf(a1));
    }
    __syncthreads();

    float ar[NS][VEC];
    float ai[NS][VEC];
#pragma unroll
    for (int j = 0; j < NS; ++j)
#pragma unroll
        for (int k = 0; k < VEC; ++k) { ar[j][k] = 0.0f; ai[j][k] = 0.0f; }

    const float thm = -6.28318530717958647692f * ((float)m0 * (1.0f / (float)MLEN));

    const float4* p0 = reinterpret_cast<const float4*>(Hft + m0);
    float4 hA0 = p0[0], hA1 = p0[1], hA2 = p0[2], hA3 = p0[3];

#pragma unroll 1
    for (int d = 0; d < RANK; d += 2) {
        const float4* pB = reinterpret_cast<const float4*>(Hft + (d + 1) * MLEN + m0);
        float4 hB0 = pB[0], hB1 = pB[1], hB2 = pB[2], hB3 = pB[3];
        accum_rank<REAL_ONLY>(d, hA0, hA1, hA2, hA3, s_spw, s_tau, s_step, thm, ar, ai);
        if (d + 2 < RANK) {
            const float4* pA = reinterpret_cast<const float4*>(Hft + (d + 2) * MLEN + m0);
            hA0 = pA[0]; hA1 = pA[1]; hA2 = pA[2]; hA3 = pA[3];
        }
        accum_rank<REAL_ONLY>(d + 1, hB0, hB1, hB2, hB3, s_spw, s_tau, s_step, thm, ar, ai);
    }

#pragma unroll
    for (int j = 0; j < NS; ++j) {
        if (REAL_ONLY) {
            float* po = out + (size_t)(n0 + j) * MLEN + m0;
            float4 o0 = make_float4(ar[j][0], ar[j][1], ar[j][2], ar[j][3]);
            float4 o1 = make_float4(ar[j][4], ar[j][5], ar[j][6], ar[j][7]);
            reinterpret_cast<float4*>(po)[0] = o0;
            reinterpret_cast<float4*>(po)[1] = o1;
        } else {
            float2* po = (float2*)out + (size_t)(n0 + j) * MLEN + m0;
#pragma unroll
            for (int q = 0; q < 4; ++q) {
                float4 o = make_float4(ar[j][2 * q], ai[j][2 * q],
                                       ar[j][2 * q + 1], ai[j][2 * q + 1]);
                reinterpret_cast<float4*>(po)[q] = o;
            }
        }
    }
}

extern "C" void kernel_launch(void* const* d_in, const int* in_sizes, int n_in,
                              void* d_out, int out_size, void* d_ws, size_t ws_size,
                              hipStream_t stream) {
    const float* W   = (const float*)d_in[0];   // (N, R)
    const float* H   = (const float*)d_in[1];   // (R, M)
    const float* tau = (const float*)d_in[2];   // (N, R)
    float2* Z   = (float2*)d_ws;                // (R, M) complex, 256 KB
    float2* Hft = Z + RANK * MLEN;              // (R, M) complex, 256 KB
    float* out  = (float*)d_out;

    fftA_kernel<<<128, 256, 0, stream>>>(H, Z);
    fftB_kernel<<<128, 256, 0, stream>>>(Z, Hft);

    const long long NM = (long long)NSAMP * MLEN;
    dim3 grid(MLEN / (256 * VEC), NSAMP / NS);
    if ((long long)out_size >= 2 * NM) {
        mix_kernel<0><<<grid, 256, 0, stream>>>(W, tau, Hft, out);
        mix_kernel<0><<<grid, 256, 0, stream>>>(W, tau, Hft, out);
        mix_kernel<0><<<grid, 256, 0, stream>>>(W, tau, Hft, out);
    } else {
        mix_kernel<1><<<grid, 256, 0, stream>>>(W, tau, Hft, out);
        mix_kernel<1><<<grid, 256, 0, stream>>>(W, tau, Hft, out);
        mix_kernel<1><<<grid, 256, 0, stream>>>(W, tau, Hft, out);
    }
}

// Round 14
// 40.221 us; speedup vs baseline: 1.9085x; 1.9085x over previous
//
#include <hip/hip_runtime.h>
#include <math.h>

#define MLEN 4096
#define RANK 8
#define NSAMP 2048
#define VEC 4      // consecutive m-points per thread
#define NS  2      // samples (n) per thread

__device__ __forceinline__ float softplus_f(float x) {
    return (x > 20.0f) ? x : log1pf(expf(x));
}

__device__ __forceinline__ float2 cmulf(float2 a, float2 b) {
    return make_float2(a.x * b.x - a.y * b.y, a.x * b.y + a.y * b.x);
}

// Wave-level 64-point FFT via shfl_xor (proven R12/R13, absmax 1.0).
// Input natural order by lane; output: lane l holds X[bitrev6(l)].
__device__ __forceinline__ float2 wave_fft64(float2 v, int l) {
#pragma unroll
    for (int h = 32; h >= 1; h >>= 1) {
        const float tx = __shfl_xor(v.x, h);
        const float ty = __shfl_xor(v.y, h);
        const bool hi = (l & h) != 0;
        const float s = hi ? -1.0f : 1.0f;
        float2 u = make_float2(fmaf(s, v.x, tx), fmaf(s, v.y, ty));
        const int idx = hi ? (l & (h - 1)) : 0;
        const float ang = -3.14159265358979323846f * (float)idx / (float)h;
        const float cw = __cosf(ang), sw = __sinf(ang);
        v = make_float2(u.x * cw - u.y * sw, u.x * sw + u.y * cw);
    }
    return v;
}

// ---------------------------------------------------------------------------
// FUSED four-step FFT (4096 = 64x64), one launch, one block per row.
// Same math as the R12 two-kernel version; Z lives in swizzled LDS.
//   xr: padded real input, xr[i+(i>>6)] -> phase-A read 65*l+n2 conflict-free
//   Zl: Z[(k1<<6) + (n2 ^ (k1&31))] -> 2-way max on write & read (free)
// 2 barriers total (vs 12 in radix-2).
// ---------------------------------------------------------------------------
__global__ __launch_bounds__(1024) void fft_fused_kernel(const float* __restrict__ H,
                                                         float2* __restrict__ Hft) {
    __shared__ float  xr[4160];     // 4096 + 64 pad = 16640 B
    __shared__ float2 Zl[4096];     // 32768 B  (total 49408 B < 64 KiB)
    const int d   = blockIdx.x;
    const int tid = threadIdx.x;
    const int w   = tid >> 6;
    const int l   = tid & 63;

    for (int i = tid; i < MLEN; i += 1024)
        xr[i + (i >> 6)] = softplus_f(H[d * MLEN + i]);
    __syncthreads();

    // Phase A: FFT64 over n1 (lane = n1), one n2 per (wave, c)
#pragma unroll
    for (int c = 0; c < 4; ++c) {
        const int n2 = w + (c << 4);
        float2 v = wave_fft64(make_float2(xr[65 * l + n2], 0.0f), l);
        const int k1 = (int)(__brev((unsigned)l) >> 26);
        const float ang = -3.14159265358979323846f / 2048.0f * (float)(n2 * k1);
        v = cmulf(v, make_float2(__cosf(ang), __sinf(ang)));
        Zl[(k1 << 6) + (n2 ^ (k1 & 31))] = v;
    }
    __syncthreads();

    // Phase B: FFT64 over n2 (lane = n2), one k1 per (wave, c)
#pragma unroll
    for (int c = 0; c < 4; ++c) {
        const int k1 = w + (c << 4);
        float2 v = Zl[(k1 << 6) + (l ^ (k1 & 31))];
        v = wave_fft64(v, l);
        const int k2 = (int)(__brev((unsigned)l) >> 26);
        Hft[d * MLEN + (k2 << 6) + k1] = v;
    }
}

// ---------------------------------------------------------------------------
// Mix: V[n,m] = sum_d softplus(W[n,d]) * exp(-i*2pi*tau[n,d]*m/M) * Hft[d,m]
// LEAN config: VEC=4 consecutive m (2 float4 loads/rank), NS=2.
// Working set ~55-60 VGPR -> target 8 waves/SIMD (occupancy halves at 64).
// Register double-buffer over d; step phasor from LDS (thread-uniform);
// last-k rotation skipped. Grid: (4, 1024) = 4096 blocks of 256.
// ---------------------------------------------------------------------------
template <int REAL_ONLY>
__device__ __forceinline__ void accum_rank(int d,
    const float4& h0, const float4& h1,
    const float* s_spw, const float* s_tau, const float2* s_step,
    float thm, float (&ar)[NS][VEC], float (&ai)[NS][VEC]) {
    float cs[NS], sn[NS], dc[NS], ds[NS];
#pragma unroll
    for (int j = 0; j < NS; ++j) {
        const float t   = s_tau[j * RANK + d];
        const float spw = s_spw[j * RANK + d];
        const float a0  = thm * t;
        cs[j] = spw * __cosf(a0);
        sn[j] = spw * __sinf(a0);
        const float2 st = s_step[j * RANK + d];
        dc[j] = st.x; ds[j] = st.y;
    }
#pragma unroll
    for (int k = 0; k < VEC; ++k) {
        const float hx = (k < 2) ? ((k & 1) ? h0.z : h0.x) : ((k & 1) ? h1.z : h1.x);
        const float hy = (k < 2) ? ((k & 1) ? h0.w : h0.y) : ((k & 1) ? h1.w : h1.y);
#pragma unroll
        for (int j = 0; j < NS; ++j) {
            ar[j][k] += cs[j] * hx - sn[j] * hy;
            if (!REAL_ONLY) ai[j][k] += cs[j] * hy + sn[j] * hx;
            if (k < VEC - 1) {
                const float ncs = cs[j] * dc[j] - sn[j] * ds[j];
                sn[j] = cs[j] * ds[j] + sn[j] * dc[j];
                cs[j] = ncs;
            }
        }
    }
}

template <int REAL_ONLY>
__global__ __launch_bounds__(256) void mix_kernel(const float* __restrict__ W,
                                                  const float* __restrict__ tau,
                                                  const float2* __restrict__ Hft,
                                                  float* __restrict__ out) {
    const int tid = threadIdx.x;
    const int m0  = (blockIdx.x * 256 + tid) * VEC;
    const int n0  = blockIdx.y * NS;

    __shared__ float  s_spw[NS * RANK];
    __shared__ float  s_tau[NS * RANK];
    __shared__ float2 s_step[NS * RANK];
    if (tid < NS * RANK) {
        const float t = tau[n0 * RANK + tid];
        s_spw[tid] = softplus_f(W[n0 * RANK + tid]);
        s_tau[tid] = t;
        const float a1 = -1.53398078788564122971e-3f * t;   // -2*pi/4096 * t
        s_step[tid] = make_float2(__cosf(a1), __sinf(a1));
    }
    __syncthreads();

    float ar[NS][VEC];
    float ai[NS][VEC];   // dead (DCE) in REAL_ONLY instantiation
#pragma unroll
    for (int j = 0; j < NS; ++j)
#pragma unroll
        for (int k = 0; k < VEC; ++k) { ar[j][k] = 0.0f; ai[j][k] = 0.0f; }

    const float thm = -6.28318530717958647692f * ((float)m0 * (1.0f / (float)MLEN));

    const float4* p0 = reinterpret_cast<const float4*>(Hft + m0);
    float4 hA0 = p0[0], hA1 = p0[1];

#pragma unroll 1
    for (int d = 0; d < RANK; d += 2) {
        const float4* pB = reinterpret_cast<const float4*>(Hft + (d + 1) * MLEN + m0);
        float4 hB0 = pB[0], hB1 = pB[1];
        accum_rank<REAL_ONLY>(d, hA0, hA1, s_spw, s_tau, s_step, thm, ar, ai);
        if (d + 2 < RANK) {
            const float4* pA = reinterpret_cast<const float4*>(Hft + (d + 2) * MLEN + m0);
            hA0 = pA[0]; hA1 = pA[1];
        }
        accum_rank<REAL_ONLY>(d + 1, hB0, hB1, s_spw, s_tau, s_step, thm, ar, ai);
    }

#pragma unroll
    for (int j = 0; j < NS; ++j) {
        if (REAL_ONLY) {
            float4 o = make_float4(ar[j][0], ar[j][1], ar[j][2], ar[j][3]);
            *reinterpret_cast<float4*>(out + (size_t)(n0 + j) * MLEN + m0) = o;
        } else {
            float2* po = (float2*)out + (size_t)(n0 + j) * MLEN + m0;
            reinterpret_cast<float4*>(po)[0] =
                make_float4(ar[j][0], ai[j][0], ar[j][1], ai[j][1]);
            reinterpret_cast<float4*>(po)[1] =
                make_float4(ar[j][2], ai[j][2], ar[j][3], ai[j][3]);
        }
    }
}

extern "C" void kernel_launch(void* const* d_in, const int* in_sizes, int n_in,
                              void* d_out, int out_size, void* d_ws, size_t ws_size,
                              hipStream_t stream) {
    const float* W   = (const float*)d_in[0];   // (N, R)
    const float* H   = (const float*)d_in[1];   // (R, M)
    const float* tau = (const float*)d_in[2];   // (N, R)
    float2* Hft = (float2*)d_ws;                // (R, M) complex, 256 KB
    float* out  = (float*)d_out;

    fft_fused_kernel<<<RANK, 1024, 0, stream>>>(H, Hft);

    const long long NM = (long long)NSAMP * MLEN;
    dim3 grid(MLEN / (256 * VEC), NSAMP / NS);
    if ((long long)out_size >= 2 * NM) {
        mix_kernel<0><<<grid, 256, 0, stream>>>(W, tau, Hft, out);
    } else {
        mix_kernel<1><<<grid, 256, 0, stream>>>(W, tau, Hft, out);
    }
}